// Round 1
// baseline (844.745 us; speedup 1.0000x reference)
//
#include <hip/hip_runtime.h>
#include <math.h>

typedef float f4 __attribute__((ext_vector_type(4)));

#define QBN_EPS 1e-4f

__global__ void qbn_zero(float* __restrict__ p, int n) {
    int i = blockIdx.x * blockDim.x + threadIdx.x;
    if (i < n) p[i] = 0.0f;
}

// Pass 1: per-channel sums and second moments.
// stats layout: [14][C] = {sum_r, sum_i, sum_j, sum_k, rr, ri, rj, rk, ii, ij, ik, jj, jk, kk}
__global__ void qbn_reduce(const float* __restrict__ x, float* __restrict__ stats,
                           int N, int C, int C4, int rows) {
    const int g = threadIdx.x % C4;      // channel group (4 channels)
    const int srow = threadIdx.x / C4;   // spatial row within block
    const long c0 = (long)g * 4;
    const long NC = (long)N * (long)C;

    f4 a[14];
#pragma unroll
    for (int t = 0; t < 14; ++t) a[t] = 0.0f;

    for (long s = (long)blockIdx.x * rows + srow; s < (long)N;
         s += (long)gridDim.x * rows) {
        const float* base = x + s * (long)C + c0;
        f4 xr = *(const f4*)(base);
        f4 xi = *(const f4*)(base + NC);
        f4 xj = *(const f4*)(base + 2 * NC);
        f4 xk = *(const f4*)(base + 3 * NC);
        a[0] += xr; a[1] += xi; a[2] += xj; a[3] += xk;
        a[4]  += xr * xr; a[5]  += xr * xi; a[6]  += xr * xj; a[7]  += xr * xk;
        a[8]  += xi * xi; a[9]  += xi * xj; a[10] += xi * xk;
        a[11] += xj * xj; a[12] += xj * xk; a[13] += xk * xk;
    }

    // reduce across the `rows` waves of the block via LDS, then atomics.
    __shared__ f4 lds[3][64];
    for (int t = 0; t < 14; ++t) {
        if (srow > 0) lds[srow - 1][g] = a[t];
        __syncthreads();
        if (srow == 0) {
            f4 v = a[t];
            for (int r = 0; r < rows - 1; ++r) v += lds[r][g];
            float* dst = stats + (long)t * C + c0;
            atomicAdd(dst + 0, v.x);
            atomicAdd(dst + 1, v.y);
            atomicAdd(dst + 2, v.z);
            atomicAdd(dst + 3, v.w);
        }
        __syncthreads();
    }
}

// Pass 2: per-channel whitening matrix, fused with gamma and beta.
// Mbuf: [16][C] (row-major 4x4), bbuf: [4][C]
__global__ void qbn_whiten(const float* __restrict__ stats,
                           const float* __restrict__ gamma,
                           const float* __restrict__ beta,
                           float* __restrict__ Mbuf, float* __restrict__ bbuf,
                           int N, int C) {
    for (int c = blockIdx.x * blockDim.x + threadIdx.x; c < C;
         c += gridDim.x * blockDim.x) {
        const float invN = 1.0f / (float)N;
        float mu[4];
#pragma unroll
        for (int p = 0; p < 4; ++p) mu[p] = stats[p * C + c] * invN;

        // TRI order: rr ri rj rk ii ij ik jj jk kk
        const int tp[10] = {0, 0, 0, 0, 1, 1, 1, 2, 2, 3};
        const int tq[10] = {0, 1, 2, 3, 1, 2, 3, 2, 3, 3};
        float v[10];
#pragma unroll
        for (int t = 0; t < 10; ++t) {
            float cov = stats[(4 + t) * C + c] * invN - mu[tp[t]] * mu[tq[t]];
            if (tp[t] == tq[t]) cov += QBN_EPS;
            v[t] = cov;
        }

        // Cholesky factor entries (match reference order of ops)
        float w_rr = sqrtf(v[0]);
        float w_ri = v[1] / w_rr;
        float w_ii = sqrtf(v[4] - w_ri * w_ri);
        float w_rj = v[2] / w_rr;
        float w_ij = (v[5] - w_ri * w_rj) / w_ii;
        float w_jj = sqrtf(v[7] - (w_ij * w_ij + w_rj * w_rj));
        float w_rk = v[3] / w_rr;
        float w_ik = (v[6] - w_ri * w_rk) / w_ii;
        float w_jk = (v[8] - (w_ij * w_ik + w_rj * w_rk)) / w_jj;
        float w_kk = sqrtf(v[9] - (w_jk * w_jk + w_ik * w_ik + w_rk * w_rk));

        float o[10];
        o[0] = 1.0f / w_rr;
        o[4] = 1.0f / w_ii;
        o[7] = 1.0f / w_jj;
        o[9] = 1.0f / w_kk;
        o[1] = -(w_ri * o[0]) / w_ii;
        o[2] = -(w_rj * o[0] + w_ij * o[1]) / w_jj;
        o[3] = -(w_rk * o[0] + w_ik * o[1] + w_jk * o[2]) / w_kk;
        o[5] = -(w_ij * o[4]) / w_jj;
        o[6] = -(w_ik * o[4] + w_jk * o[5]) / w_kk;
        o[8] = -(w_jk * o[7]) / w_kk;

        const int sym[4][4] = {{0, 1, 2, 3}, {1, 4, 5, 6}, {2, 5, 7, 8}, {3, 6, 8, 9}};
        float M[4][4];
#pragma unroll
        for (int p = 0; p < 4; ++p) {
#pragma unroll
            for (int s = 0; s < 4; ++s) {
                float acc = 0.0f;
#pragma unroll
                for (int q = 0; q < 4; ++q)
                    acc += gamma[sym[p][q] * C + c] * o[sym[q][s]];
                M[p][s] = acc;
                Mbuf[(p * 4 + s) * C + c] = acc;
            }
        }
#pragma unroll
        for (int p = 0; p < 4; ++p) {
            float b = beta[p * C + c];
#pragma unroll
            for (int s = 0; s < 4; ++s) b -= M[p][s] * mu[s];
            bbuf[p * C + c] = b;
        }
    }
}

// Pass 3: out[p] = sum_s M[p][s] * x[s] + b'[p]
__global__ void qbn_apply(const float* __restrict__ x,
                          const float* __restrict__ Mbuf,
                          const float* __restrict__ bbuf,
                          float* __restrict__ out,
                          int N, int C, int C4, int rows) {
    const int g = threadIdx.x % C4;
    const int srow = threadIdx.x / C4;
    const long c0 = (long)g * 4;
    const long NC = (long)N * (long)C;

    f4 M[4][4], b[4];
#pragma unroll
    for (int p = 0; p < 4; ++p) {
#pragma unroll
        for (int q = 0; q < 4; ++q)
            M[p][q] = *(const f4*)(Mbuf + (long)(p * 4 + q) * C + c0);
        b[p] = *(const f4*)(bbuf + (long)p * C + c0);
    }

    for (long s = (long)blockIdx.x * rows + srow; s < (long)N;
         s += (long)gridDim.x * rows) {
        const float* base = x + s * (long)C + c0;
        f4 xr = *(const f4*)(base);
        f4 xi = *(const f4*)(base + NC);
        f4 xj = *(const f4*)(base + 2 * NC);
        f4 xk = *(const f4*)(base + 3 * NC);
        float* obase = out + s * (long)C + c0;
#pragma unroll
        for (int p = 0; p < 4; ++p) {
            f4 o = M[p][0] * xr + M[p][1] * xi + M[p][2] * xj + M[p][3] * xk + b[p];
            *(f4*)(obase + (long)p * NC) = o;
        }
    }
}

extern "C" void kernel_launch(void* const* d_in, const int* in_sizes, int n_in,
                              void* d_out, int out_size, void* d_ws, size_t ws_size,
                              hipStream_t stream) {
    const float* x = (const float*)d_in[0];
    const float* gamma = (const float*)d_in[1];
    const float* beta = (const float*)d_in[2];
    float* out = (float*)d_out;

    const int C = in_sizes[1] / 10;          // 256
    const int N = in_sizes[0] / (4 * C);     // 100352
    const int C4 = C / 4;                    // 64
    const int rows = 256 / C4;               // 4 spatial rows per block

    float* stats = (float*)d_ws;             // [14][C]
    float* Mbuf = stats + 14 * C;            // [16][C]
    float* bbuf = Mbuf + 16 * C;             // [4][C]

    const int nz = 14 * C;
    qbn_zero<<<(nz + 255) / 256, 256, 0, stream>>>(stats, nz);
    qbn_reduce<<<784, 256, 0, stream>>>(x, stats, N, C, C4, rows);
    qbn_whiten<<<1, 256, 0, stream>>>(stats, gamma, beta, Mbuf, bbuf, N, C);
    qbn_apply<<<1568, 256, 0, stream>>>(x, Mbuf, bbuf, out, N, C, C4, rows);
}